// Round 1
// baseline (373.377 us; speedup 1.0000x reference)
//
#include <hip/hip_runtime.h>

typedef __attribute__((ext_vector_type(8))) __bf16 bf16x8;
typedef __attribute__((ext_vector_type(4))) float f32x4;

#define MFMA16(a,b,c) __builtin_amdgcn_mfma_f32_16x16x32_bf16((a),(b),(c),0,0,0)

__device__ __forceinline__ short f2bf(float f){
  union { float f; unsigned u; } x; x.f = f;
  return (short)((x.u + 0x7fffu + ((x.u >> 16) & 1u)) >> 16);
}

__device__ __forceinline__ void gld16(void* lds, const void* g){
  __builtin_amdgcn_global_load_lds(
      (const __attribute__((address_space(1))) unsigned*)g,
      (__attribute__((address_space(3))) unsigned*)lds, 16, 0, 0);
}

// ---------------- elementwise converts / transposes ----------------

__global__ __launch_bounds__(256) void k_cvt8(const float* __restrict__ x,
                                              short* __restrict__ xb){
  long i = (long)blockIdx.x * 256 + threadIdx.x;       // groups of 8
  const float4* xv = (const float4*)x;
  float4 a = xv[2*i], c = xv[2*i+1];
  short s[8] = {f2bf(a.x),f2bf(a.y),f2bf(a.z),f2bf(a.w),
                f2bf(c.x),f2bf(c.y),f2bf(c.z),f2bf(c.w)};
  *(uint4*)&xb[8*i] = *(uint4*)s;
}

// W fp32 [2048][N] row-major -> Wt bf16 [N][2048]
__global__ void k_wt(const float* __restrict__ W, short* __restrict__ Wt, int N){
  __shared__ float tile[32][33];
  int tx = threadIdx.x, ty = threadIdx.y;
  int k0 = blockIdx.y*32, n0 = blockIdx.x*32;
  for (int j=0;j<32;j+=8)
    tile[ty+j][tx] = W[(size_t)(k0+ty+j)*N + n0 + tx];
  __syncthreads();
  for (int j=0;j<32;j+=8)
    Wt[(size_t)(n0+ty+j)*2048 + k0 + tx] = f2bf(tile[tx][ty+j]);
}

__global__ void k_bias(const float* __restrict__ bq, const float* __restrict__ bk,
                       const float* __restrict__ bv, float* __restrict__ outb){
  int i = blockIdx.x*256 + threadIdx.x;   // 0..3071
  float v = (i < 2048) ? bq[i] : (i < 2560 ? bk[i-2048] : bv[i-2560]);
  outb[i] = v;
}

// v-part of qkv (bf16, rows 4096, cols 2560..3071 of ld 3072) -> Vt[b][kvh][d][t]
__global__ void k_vt(const short* __restrict__ qkv, short* __restrict__ Vt){
  __shared__ short tile[32][33];
  int tx = threadIdx.x, ty = threadIdx.y;
  int t0 = blockIdx.x*32, c0 = blockIdx.y*32;
  for (int j=0;j<32;j+=8)
    tile[ty+j][tx] = qkv[(size_t)(t0+ty+j)*3072 + 2560 + c0 + tx];
  __syncthreads();
  int b = t0 >> 11, t_in_b = t0 & 2047;
  for (int j=0;j<32;j+=8){
    int col = c0 + ty + j;               // 0..511
    int kvh = col >> 7, d = col & 127;
    Vt[((size_t)((b*4 + kvh)*128 + d))*2048 + t_in_b + tx] = tile[tx][ty+j];
  }
}

// ---------------- m97-style GEMM: C = A * Bt^T + bias ----------------
// A [M][K] bf16, Bt [N][K] bf16, bias fp32 [N]. OUT_BF16: short out else float.
template<int OUT_BF16>
__global__ __launch_bounds__(256) void gemm_bt(const short* __restrict__ A,
    const short* __restrict__ Bt, const float* __restrict__ bias,
    void* __restrict__ Cv, int M, int N, int K){
  __shared__ short As[128*32];
  __shared__ short Bs[128*32];
  const int tid = threadIdx.x;
  const int w = tid >> 6, lane = tid & 63, l15 = lane & 15, quad = lane >> 4;
  const int wr = w >> 1, wc = w & 1;
  const int m0 = blockIdx.y*128, n0 = blockIdx.x*128;
  const int lrow = lane >> 2, lcol = (lane & 3)*8;
  const short* Ag = A  + (size_t)(m0 + w*32 + lrow)*K + lcol;
  const short* Bg = Bt + (size_t)(n0 + w*32 + lrow)*K + lcol;
  short* AsW0 = &As[(w*32)*32];
  short* AsW1 = &As[(w*32+16)*32];
  short* BsW0 = &Bs[(w*32)*32];
  short* BsW1 = &Bs[(w*32+16)*32];
  const size_t r16K = (size_t)16*K;
  f32x4 acc[4][4] = {};
  for (int kt = 0; kt < K; kt += 32){
    gld16(AsW0, Ag + kt);
    gld16(AsW1, Ag + kt + r16K);
    gld16(BsW0, Bg + kt);
    gld16(BsW1, Bg + kt + r16K);
    __syncthreads();
    bf16x8 af[4], bfr[4];
#pragma unroll
    for (int i=0;i<4;i++){
      af[i]  = *(const bf16x8*)&As[(wr*64 + i*16 + l15)*32 + quad*8];
      bfr[i] = *(const bf16x8*)&Bs[(wc*64 + i*16 + l15)*32 + quad*8];
    }
#pragma unroll
    for (int mi=0;mi<4;mi++)
#pragma unroll
      for (int nj=0;nj<4;nj++)
        acc[mi][nj] = MFMA16(af[mi], bfr[nj], acc[mi][nj]);
    __syncthreads();
  }
  float bv[4];
#pragma unroll
  for (int nj=0;nj<4;nj++) bv[nj] = bias[n0 + wc*64 + nj*16 + l15];
#pragma unroll
  for (int mi=0;mi<4;mi++){
    int row = m0 + wr*64 + mi*16 + quad*4;
#pragma unroll
    for (int nj=0;nj<4;nj++){
      int col = n0 + wc*64 + nj*16 + l15;
#pragma unroll
      for (int r=0;r<4;r++){
        float v = acc[mi][nj][r] + bv[nj];
        if (OUT_BF16) ((short*)Cv)[(size_t)(row+r)*N + col] = f2bf(v);
        else          ((float*)Cv)[(size_t)(row+r)*N + col] = v;
      }
    }
  }
}

// ---------------- flash-style causal GQA attention ----------------
// qkv bf16 [4096][3072] (q: col h*128, k: 2048+kvh*128, v unused here)
// Vt bf16 [B][KVH][128][2048];  attn out bf16 [4096][2048]
// BQ=128 (block), BS=32 (s-tile). 4 waves x 32 q-rows. Fixed-zero softmax max.
__global__ __launch_bounds__(256) void k_attn(const short* __restrict__ qkv,
                                              const short* __restrict__ Vt,
                                              short* __restrict__ attn){
  constexpr int LDQ = 136, LDK = 136, LDV = 40, LDP = 40;
  constexpr float COEF = 0.12752365f;     // (1/sqrt(128)) * log2(e)
  __shared__ short smem[17408];           // 34816 B; Qs overlaid by Ks/Vs/Ps
  short* Qs = smem;                       // [128][136]
  short* Ks = smem;                       // [32][136]  = 4352 shorts
  short* Vs = smem + 4352;                // [128][40]  = 5120 shorts
  short* Ps = smem + 9472;                // [128][40]  = 5120 shorts
  const int tid = threadIdx.x, w = tid >> 6, lane = tid & 63;
  const int l15 = lane & 15, quad = lane >> 4;
  const int qt = blockIdx.x, h = blockIdx.y, b = blockIdx.z, kvh = h >> 2;
  const int q0 = qt*128;

  { // stage Q [128][128]
    int r16 = tid >> 4, c8 = (tid & 15)*8;
    const short* src = qkv + ((size_t)(b*2048 + q0 + r16))*3072 + h*128 + c8;
    short* dst = &Qs[r16*LDQ + c8];
#pragma unroll
    for (int i=0;i<8;i++)
      *(uint4*)(dst + i*16*LDQ) = *(const uint4*)(src + (size_t)i*16*3072);
  }
  __syncthreads();
  bf16x8 aq[2][4];                        // Q fragments live in registers
#pragma unroll
  for (int mi=0;mi<2;mi++)
#pragma unroll
    for (int d=0; d<4; d++)
      aq[mi][d] = *(const bf16x8*)&Qs[(w*32 + mi*16 + l15)*LDQ + d*32 + quad*8];
  __syncthreads();                        // Qs region now reusable

  f32x4 acc_o[2][8] = {};
  float lsum[2][4] = {};
  const int nst = qt*4 + 4;
  for (int st = 0; st < nst; st++){
    const int s0 = st*32;
    { // stage Ks [32][128] and Vs [128][32]
      int r = tid >> 4, c8 = (tid & 15)*8;
      const short* src = qkv + ((size_t)(b*2048 + s0 + r))*3072 + 2048 + kvh*128 + c8;
      *(uint4*)&Ks[r*LDK + c8]      = *(const uint4*)src;
      *(uint4*)&Ks[(r+16)*LDK + c8] = *(const uint4*)(src + (size_t)16*3072);
      int vr = tid >> 2, vc8 = (tid & 3)*8;
      const short* vsrc = Vt + ((size_t)((b*4 + kvh)*128 + vr))*2048 + s0 + vc8;
      *(uint4*)&Vs[vr*LDV + vc8]      = *(const uint4*)vsrc;
      *(uint4*)&Vs[(vr+64)*LDV + vc8] = *(const uint4*)(vsrc + (size_t)64*2048);
    }
    __syncthreads();
    // S = Q K^T (128 x 32 strip)
    f32x4 accs[2][2] = {};
#pragma unroll
    for (int d=0; d<4; d++){
      bf16x8 bk0 = *(const bf16x8*)&Ks[( 0 + l15)*LDK + d*32 + quad*8];
      bf16x8 bk1 = *(const bf16x8*)&Ks[(16 + l15)*LDK + d*32 + quad*8];
      accs[0][0] = MFMA16(aq[0][d], bk0, accs[0][0]);
      accs[0][1] = MFMA16(aq[0][d], bk1, accs[0][1]);
      accs[1][0] = MFMA16(aq[1][d], bk0, accs[1][0]);
      accs[1][1] = MFMA16(aq[1][d], bk1, accs[1][1]);
    }
    const bool need_mask = (st >= qt*4);
#pragma unroll
    for (int mi=0;mi<2;mi++)
#pragma unroll
      for (int nj=0;nj<2;nj++){
        int qrb = w*32 + mi*16 + quad*4;        // local q-row base
        int s_g = s0 + nj*16 + l15;             // global s
        short* pdst = &Ps[qrb*LDP + nj*16 + l15];
#pragma unroll
        for (int r=0;r<4;r++){
          float sval = accs[mi][nj][r];
          if (need_mask && (s_g > q0 + qrb + r)) sval = -INFINITY;
          float p = exp2f(sval * COEF);
          lsum[mi][r] += p;
          pdst[r*LDP] = f2bf(p);
        }
      }
    __syncthreads();                            // P visible (and no reordering)
    // O += P V
#pragma unroll
    for (int mi=0;mi<2;mi++){
      bf16x8 ap = *(const bf16x8*)&Ps[(w*32 + mi*16 + l15)*LDP + quad*8];
#pragma unroll
      for (int dj=0;dj<8;dj++){
        bf16x8 bvv = *(const bf16x8*)&Vs[(dj*16 + l15)*LDV + quad*8];
        acc_o[mi][dj] = MFMA16(ap, bvv, acc_o[mi][dj]);
      }
    }
    __syncthreads();                            // protect Ks/Vs/Ps before restage
  }
  // reduce row-sums over the 16 lanes holding each row's columns
#pragma unroll
  for (int mi=0;mi<2;mi++)
#pragma unroll
    for (int r=0;r<4;r++){
      float s = lsum[mi][r];
      s += __shfl_xor(s, 1); s += __shfl_xor(s, 2);
      s += __shfl_xor(s, 4); s += __shfl_xor(s, 8);
      lsum[mi][r] = 1.0f / s;
    }
#pragma unroll
  for (int mi=0;mi<2;mi++){
    int row = b*2048 + q0 + w*32 + mi*16 + quad*4;
#pragma unroll
    for (int dj=0;dj<8;dj++){
      int col = h*128 + dj*16 + l15;
#pragma unroll
      for (int r=0;r<4;r++)
        attn[(size_t)(row+r)*2048 + col] = f2bf(acc_o[mi][dj][r] * lsum[mi][r]);
    }
  }
}

// ---------------- launcher ----------------
extern "C" void kernel_launch(void* const* d_in, const int* in_sizes, int n_in,
                              void* d_out, int out_size, void* d_ws, size_t ws_size,
                              hipStream_t stream){
  const float* x  = (const float*)d_in[0];
  const float* Wq = (const float*)d_in[1];
  const float* bq = (const float*)d_in[2];
  const float* Wk = (const float*)d_in[3];
  const float* bk = (const float*)d_in[4];
  const float* Wv = (const float*)d_in[5];
  const float* bv = (const float*)d_in[6];
  const float* Wo = (const float*)d_in[7];
  const float* bo = (const float*)d_in[8];
  float* out = (float*)d_out;
  char* ws = (char*)d_ws;

  short* xb    = (short*)(ws + 0);                        // 16 MB
  short* WtQKV = (short*)(ws + (size_t)16*1024*1024);     // 12 MB [3072][2048]
  short* WoT   = (short*)(ws + (size_t)28*1024*1024);     //  8 MB [2048][2048]
  float* biasQ = (float*)(ws + (size_t)36*1024*1024);     // 12 KB
  short* qkv   = (short*)(ws + (size_t)37*1024*1024);     // 24 MB [4096][3072]
  short* Vt    = (short*)(ws + (size_t)61*1024*1024);     //  4 MB [B][KVH][128][2048]
  short* attn  = (short*)(ws + 0);                        // overlay xb (disjoint lifetime)

  k_cvt8<<<4096, 256, 0, stream>>>(x, xb);
  k_wt<<<dim3(64,64), dim3(32,8), 0, stream>>>(Wq, WtQKV, 2048);
  k_wt<<<dim3(16,64), dim3(32,8), 0, stream>>>(Wk, WtQKV + (size_t)2048*2048, 512);
  k_wt<<<dim3(16,64), dim3(32,8), 0, stream>>>(Wv, WtQKV + (size_t)2560*2048, 512);
  k_wt<<<dim3(64,64), dim3(32,8), 0, stream>>>(Wo, WoT, 2048);
  k_bias<<<12, 256, 0, stream>>>(bq, bk, bv, biasQ);
  gemm_bt<1><<<dim3(24,32), 256, 0, stream>>>(xb, WtQKV, biasQ, qkv, 4096, 3072, 2048);
  k_vt<<<dim3(128,16), dim3(32,8), 0, stream>>>(qkv, Vt);
  k_attn<<<dim3(16,16,2), 256, 0, stream>>>(qkv, Vt, attn);
  gemm_bt<0><<<dim3(16,32), 256, 0, stream>>>(attn, WoT, bo, out, 4096, 2048, 2048);
}

// Round 2
// 370.727 us; speedup vs baseline: 1.0071x; 1.0071x over previous
//
#include <hip/hip_runtime.h>

typedef __attribute__((ext_vector_type(8))) __bf16 bf16x8;
typedef __attribute__((ext_vector_type(4))) float f32x4;
typedef __attribute__((ext_vector_type(4))) short short4v;

#define MFMA16(a,b,c)  __builtin_amdgcn_mfma_f32_16x16x32_bf16((a),(b),(c),0,0,0)
#define MFMA16K(a,b,c) __builtin_amdgcn_mfma_f32_16x16x16bf16_1k((a),(b),(c),0,0,0)

__device__ __forceinline__ short f2bf(float f){
  union { float f; unsigned u; } x; x.f = f;
  return (short)((x.u + 0x7fffu + ((x.u >> 16) & 1u)) >> 16);
}
__device__ __forceinline__ unsigned bits(float f){
  union { float f; unsigned u; } x; x.f = f; return x.u;
}

__device__ __forceinline__ void gld16(void* lds, const void* g){
  __builtin_amdgcn_global_load_lds(
      (const __attribute__((address_space(1))) unsigned*)g,
      (__attribute__((address_space(3))) unsigned*)lds, 16, 0, 0);
}

// ---------------- elementwise converts / transposes ----------------

__global__ __launch_bounds__(256) void k_cvt8(const float* __restrict__ x,
                                              short* __restrict__ xb){
  long i = (long)blockIdx.x * 256 + threadIdx.x;       // groups of 8
  const float4* xv = (const float4*)x;
  float4 a = xv[2*i], c = xv[2*i+1];
  short s[8] = {f2bf(a.x),f2bf(a.y),f2bf(a.z),f2bf(a.w),
                f2bf(c.x),f2bf(c.y),f2bf(c.z),f2bf(c.w)};
  *(uint4*)&xb[8*i] = *(uint4*)s;
}

// W fp32 [2048][N] row-major -> Wt bf16 [N][2048]
__global__ void k_wt(const float* __restrict__ W, short* __restrict__ Wt, int N){
  __shared__ float tile[32][33];
  int tx = threadIdx.x, ty = threadIdx.y;
  int k0 = blockIdx.y*32, n0 = blockIdx.x*32;
  for (int j=0;j<32;j+=8)
    tile[ty+j][tx] = W[(size_t)(k0+ty+j)*N + n0 + tx];
  __syncthreads();
  for (int j=0;j<32;j+=8)
    Wt[(size_t)(n0+ty+j)*2048 + k0 + tx] = f2bf(tile[tx][ty+j]);
}

__global__ void k_bias(const float* __restrict__ bq, const float* __restrict__ bk,
                       const float* __restrict__ bv, float* __restrict__ outb){
  int i = blockIdx.x*256 + threadIdx.x;   // 0..3071
  float v = (i < 2048) ? bq[i] : (i < 2560 ? bk[i-2048] : bv[i-2560]);
  outb[i] = v;
}

// v-part of qkv (bf16, rows 4096, cols 2560..3071 of ld 3072) -> Vt[b][kvh][d][t]
__global__ void k_vt(const short* __restrict__ qkv, short* __restrict__ Vt){
  __shared__ short tile[32][33];
  int tx = threadIdx.x, ty = threadIdx.y;
  int t0 = blockIdx.x*32, c0 = blockIdx.y*32;
  for (int j=0;j<32;j+=8)
    tile[ty+j][tx] = qkv[(size_t)(t0+ty+j)*3072 + 2560 + c0 + tx];
  __syncthreads();
  int b = t0 >> 11, t_in_b = t0 & 2047;
  for (int j=0;j<32;j+=8){
    int col = c0 + ty + j;               // 0..511
    int kvh = col >> 7, d = col & 127;
    Vt[((size_t)((b*4 + kvh)*128 + d))*2048 + t_in_b + tx] = tile[tx][ty+j];
  }
}

// ---------------- m97-style GEMM: C = A * Bt^T + bias ----------------
template<int OUT_BF16>
__global__ __launch_bounds__(256) void gemm_bt(const short* __restrict__ A,
    const short* __restrict__ Bt, const float* __restrict__ bias,
    void* __restrict__ Cv, int M, int N, int K){
  __shared__ short As[128*32];
  __shared__ short Bs[128*32];
  const int tid = threadIdx.x;
  const int w = tid >> 6, lane = tid & 63, l15 = lane & 15, quad = lane >> 4;
  const int wr = w >> 1, wc = w & 1;
  const int m0 = blockIdx.y*128, n0 = blockIdx.x*128;
  const int lrow = lane >> 2, lcol = (lane & 3)*8;
  const short* Ag = A  + (size_t)(m0 + w*32 + lrow)*K + lcol;
  const short* Bg = Bt + (size_t)(n0 + w*32 + lrow)*K + lcol;
  short* AsW0 = &As[(w*32)*32];
  short* AsW1 = &As[(w*32+16)*32];
  short* BsW0 = &Bs[(w*32)*32];
  short* BsW1 = &Bs[(w*32+16)*32];
  const size_t r16K = (size_t)16*K;
  f32x4 acc[4][4] = {};
  for (int kt = 0; kt < K; kt += 32){
    gld16(AsW0, Ag + kt);
    gld16(AsW1, Ag + kt + r16K);
    gld16(BsW0, Bg + kt);
    gld16(BsW1, Bg + kt + r16K);
    __syncthreads();
    bf16x8 af[4], bfr[4];
#pragma unroll
    for (int i=0;i<4;i++){
      af[i]  = *(const bf16x8*)&As[(wr*64 + i*16 + l15)*32 + quad*8];
      bfr[i] = *(const bf16x8*)&Bs[(wc*64 + i*16 + l15)*32 + quad*8];
    }
#pragma unroll
    for (int mi=0;mi<4;mi++)
#pragma unroll
      for (int nj=0;nj<4;nj++)
        acc[mi][nj] = MFMA16(af[mi], bfr[nj], acc[mi][nj]);
    __syncthreads();
  }
  float bv[4];
#pragma unroll
  for (int nj=0;nj<4;nj++) bv[nj] = bias[n0 + wc*64 + nj*16 + l15];
#pragma unroll
  for (int mi=0;mi<4;mi++){
    int row = m0 + wr*64 + mi*16 + quad*4;
#pragma unroll
    for (int nj=0;nj<4;nj++){
      int col = n0 + wc*64 + nj*16 + l15;
#pragma unroll
      for (int r=0;r<4;r++){
        float v = acc[mi][nj][r] + bv[nj];
        if (OUT_BF16) ((short*)Cv)[(size_t)(row+r)*N + col] = f2bf(v);
        else          ((float*)Cv)[(size_t)(row+r)*N + col] = v;
      }
    }
  }
}

// ---------------- flash-style causal GQA attention, transposed-S chain ------
// qkv bf16 [4096][3072]; Vt bf16 [B][KVH][128][2048]; attn bf16 [4096][2048]
// Block: 128 q rows, 4 waves x 32 q. BS=32 s per iter.
// S^T = K * Q^T via 16x16x32 (C layout == B-operand layout of 16x16x16),
// P=exp(S^T) stays in registers, O^T += V^T * P^T via 16x16x16. No P in LDS.
__global__ __launch_bounds__(256) void k_attn(const short* __restrict__ qkv,
                                              const short* __restrict__ Vt,
                                              short* __restrict__ attn){
  constexpr int LDK = 136, LDV = 40;
  constexpr float COEF = 0.12752365f;     // (1/sqrt(128)) * log2(e)
  __shared__ short Ks[32*LDK];            // K tile  [32 s][128 d]
  __shared__ short Vs[128*LDV];           // V^T tile [128 d][32 s]
  const int tid = threadIdx.x, w = tid >> 6, lane = tid & 63;
  const int l15 = lane & 15, quad = lane >> 4;
  const int qt = 15 - blockIdx.x;         // heavy blocks dispatch first
  const int h = blockIdx.y, b = blockIdx.z, kvh = h >> 2;
  const int q0 = qt*128;
  const int qw = q0 + w*32;               // this wave's first q row

  // Q fragments straight from global (B-operand layout: lane q=l15, k contiguous)
  bf16x8 qf[2][4];
  {
    const short* qbase = qkv + ((size_t)(b*2048 + qw + l15))*3072 + h*128 + quad*8;
#pragma unroll
    for (int qs=0;qs<2;qs++)
#pragma unroll
      for (int d4=0;d4<4;d4++)
        qf[qs][d4] = *(const bf16x8*)(qbase + (size_t)qs*16*3072 + d4*32);
  }

  // staging addresses
  const int kr = tid >> 4, kc8 = (tid & 15)*8;          // Ks: 32 x 128
  const short* ksrc = qkv + ((size_t)(b*2048 + kr))*3072 + 2048 + kvh*128 + kc8;
  short* kdst0 = &Ks[kr*LDK + kc8];
  short* kdst1 = &Ks[(kr+16)*LDK + kc8];
  const int vr = tid >> 2, vc8 = (tid & 3)*8;           // Vs: 128 x 32
  const short* vsrc = Vt + ((size_t)((b*4 + kvh)*128 + vr))*2048 + vc8;
  short* vdst0 = &Vs[vr*LDV + vc8];
  short* vdst1 = &Vs[(vr+64)*LDV + vc8];

  f32x4 accO[2][8] = {};                  // O^T: lane q=l15, d=dt*16+quad*4+r
  float lsum[2] = {0.f, 0.f};
  const int qg = qw + l15;                // base for qs=0; qs=1 adds 16
  const int nst = qt*4 + 4;

  for (int st = 0; st < nst; st++){
    const int s0 = st*32;
    { // stage K and V^T tiles
      const short* ks = ksrc + (size_t)s0*3072;
      *(uint4*)kdst0 = *(const uint4*)ks;
      *(uint4*)kdst1 = *(const uint4*)(ks + (size_t)16*3072);
      *(uint4*)vdst0 = *(const uint4*)(vsrc + s0);
      *(uint4*)vdst1 = *(const uint4*)(vsrc + s0 + (size_t)64*2048);
    }
    __syncthreads();
    if (s0 <= qw + 31){                   // wave-uniform: any unmasked rows?
      short4v pf[2][2];                   // [qs][sub]
#pragma unroll
      for (int qs=0;qs<2;qs++){
        f32x4 sa[2] = {};                 // S^T accum, 2 s-subtiles of 16
#pragma unroll
        for (int d4=0;d4<4;d4++){
          bf16x8 kf0 = *(const bf16x8*)&Ks[( 0 + l15)*LDK + d4*32 + quad*8];
          bf16x8 kf1 = *(const bf16x8*)&Ks[(16 + l15)*LDK + d4*32 + quad*8];
          sa[0] = MFMA16(kf0, qf[qs][d4], sa[0]);
          sa[1] = MFMA16(kf1, qf[qs][d4], sa[1]);
        }
        const int qmin = qw + qs*16;
        const bool mneed = (s0 + 31 > qmin);
        const int qgl = qg + qs*16;
#pragma unroll
        for (int sub=0;sub<2;sub++){
          float p[4];
#pragma unroll
          for (int r=0;r<4;r++){
            float e = __builtin_amdgcn_exp2f(sa[sub][r] * COEF);
            int sg = s0 + sub*16 + quad*4 + r;
            if (mneed && (sg > qgl)) e = 0.f;
            p[r] = e;
          }
          lsum[qs] += (p[0]+p[1]) + (p[2]+p[3]);
          union { unsigned u[2]; short4v s; } pk;
          pk.u[0] = __builtin_amdgcn_perm(bits(p[1]), bits(p[0]), 0x07060302u);
          pk.u[1] = __builtin_amdgcn_perm(bits(p[3]), bits(p[2]), 0x07060302u);
          pf[qs][sub] = pk.s;
        }
      }
      // O^T += V^T * P^T  (V frag shared across both q-subtiles)
#pragma unroll
      for (int sub=0;sub<2;sub++){
#pragma unroll
        for (int dt=0;dt<8;dt++){
          short4v vf = *(const short4v*)&Vs[(dt*16 + l15)*LDV + sub*16 + quad*4];
          accO[0][dt] = MFMA16K(vf, pf[0][sub], accO[0][dt]);
          accO[1][dt] = MFMA16K(vf, pf[1][sub], accO[1][dt]);
        }
      }
    }
    __syncthreads();
  }

  // normalize and store; lane's q is fixed, sum sits across the 4 quads
#pragma unroll
  for (int qs=0;qs<2;qs++){
    float s = lsum[qs];
    s += __shfl_xor(s, 16);
    s += __shfl_xor(s, 32);
    float inv = 1.0f / s;
    short* obase = attn + ((size_t)(b*2048 + qw + qs*16 + l15))*2048
                 + h*128 + quad*4;
#pragma unroll
    for (int dt=0;dt<8;dt++){
      float o0 = accO[qs][dt][0]*inv, o1 = accO[qs][dt][1]*inv;
      float o2 = accO[qs][dt][2]*inv, o3 = accO[qs][dt][3]*inv;
      union { unsigned u[2]; short4v s; } ok;
      ok.u[0] = __builtin_amdgcn_perm(bits(o1), bits(o0), 0x07060302u);
      ok.u[1] = __builtin_amdgcn_perm(bits(o3), bits(o2), 0x07060302u);
      *(short4v*)(obase + dt*16) = ok.s;
    }
  }
}

// ---------------- launcher ----------------
extern "C" void kernel_launch(void* const* d_in, const int* in_sizes, int n_in,
                              void* d_out, int out_size, void* d_ws, size_t ws_size,
                              hipStream_t stream){
  const float* x  = (const float*)d_in[0];
  const float* Wq = (const float*)d_in[1];
  const float* bq = (const float*)d_in[2];
  const float* Wk = (const float*)d_in[3];
  const float* bk = (const float*)d_in[4];
  const float* Wv = (const float*)d_in[5];
  const float* bv = (const float*)d_in[6];
  const float* Wo = (const float*)d_in[7];
  const float* bo = (const float*)d_in[8];
  float* out = (float*)d_out;
  char* ws = (char*)d_ws;

  short* xb    = (short*)(ws + 0);                        // 16 MB
  short* WtQKV = (short*)(ws + (size_t)16*1024*1024);     // 12 MB [3072][2048]
  short* WoT   = (short*)(ws + (size_t)28*1024*1024);     //  8 MB [2048][2048]
  float* biasQ = (float*)(ws + (size_t)36*1024*1024);     // 12 KB
  short* qkv   = (short*)(ws + (size_t)37*1024*1024);     // 24 MB [4096][3072]
  short* Vt    = (short*)(ws + (size_t)61*1024*1024);     //  4 MB [B][KVH][128][2048]
  short* attn  = (short*)(ws + 0);                        // overlay xb (disjoint lifetime)

  k_cvt8<<<4096, 256, 0, stream>>>(x, xb);
  k_wt<<<dim3(64,64), dim3(32,8), 0, stream>>>(Wq, WtQKV, 2048);
  k_wt<<<dim3(16,64), dim3(32,8), 0, stream>>>(Wk, WtQKV + (size_t)2048*2048, 512);
  k_wt<<<dim3(16,64), dim3(32,8), 0, stream>>>(Wv, WtQKV + (size_t)2560*2048, 512);
  k_wt<<<dim3(64,64), dim3(32,8), 0, stream>>>(Wo, WoT, 2048);
  k_bias<<<12, 256, 0, stream>>>(bq, bk, bv, biasQ);
  gemm_bt<1><<<dim3(24,32), 256, 0, stream>>>(xb, WtQKV, biasQ, qkv, 4096, 3072, 2048);
  k_vt<<<dim3(128,16), dim3(32,8), 0, stream>>>(qkv, Vt);
  k_attn<<<dim3(16,16,2), 256, 0, stream>>>(qkv, Vt, attn);
  gemm_bt<0><<<dim3(16,32), 256, 0, stream>>>(attn, WoT, bo, out, 4096, 2048, 2048);
}

// Round 3
// 355.162 us; speedup vs baseline: 1.0513x; 1.0438x over previous
//
#include <hip/hip_runtime.h>

typedef __attribute__((ext_vector_type(8))) __bf16 bf16x8;
typedef __attribute__((ext_vector_type(4))) float f32x4;
typedef __attribute__((ext_vector_type(4))) short short4v;

#define MFMA16(a,b,c)  __builtin_amdgcn_mfma_f32_16x16x32_bf16((a),(b),(c),0,0,0)
#define MFMA16K(a,b,c) __builtin_amdgcn_mfma_f32_16x16x16bf16_1k((a),(b),(c),0,0,0)

__device__ __forceinline__ short f2bf(float f){
  union { float f; unsigned u; } x; x.f = f;
  return (short)((x.u + 0x7fffu + ((x.u >> 16) & 1u)) >> 16);
}
__device__ __forceinline__ unsigned bits(float f){
  union { float f; unsigned u; } x; x.f = f; return x.u;
}

__device__ __forceinline__ void gld16(void* lds, const void* g){
  __builtin_amdgcn_global_load_lds(
      (const __attribute__((address_space(1))) unsigned*)g,
      (__attribute__((address_space(3))) unsigned*)lds, 16, 0, 0);
}

// ---------------- elementwise converts / transposes ----------------

__global__ __launch_bounds__(256) void k_cvt8(const float* __restrict__ x,
                                              short* __restrict__ xb){
  long i = (long)blockIdx.x * 256 + threadIdx.x;       // groups of 8
  const float4* xv = (const float4*)x;
  float4 a = xv[2*i], c = xv[2*i+1];
  short s[8] = {f2bf(a.x),f2bf(a.y),f2bf(a.z),f2bf(a.w),
                f2bf(c.x),f2bf(c.y),f2bf(c.z),f2bf(c.w)};
  *(uint4*)&xb[8*i] = *(uint4*)s;
}

// W fp32 [2048][N] row-major -> Wt bf16 [N][2048]
__global__ void k_wt(const float* __restrict__ W, short* __restrict__ Wt, int N){
  __shared__ float tile[32][33];
  int tx = threadIdx.x, ty = threadIdx.y;
  int k0 = blockIdx.y*32, n0 = blockIdx.x*32;
  for (int j=0;j<32;j+=8)
    tile[ty+j][tx] = W[(size_t)(k0+ty+j)*N + n0 + tx];
  __syncthreads();
  for (int j=0;j<32;j+=8)
    Wt[(size_t)(n0+ty+j)*2048 + k0 + tx] = f2bf(tile[tx][ty+j]);
}

__global__ void k_bias(const float* __restrict__ bq, const float* __restrict__ bk,
                       const float* __restrict__ bv, float* __restrict__ outb){
  int i = blockIdx.x*256 + threadIdx.x;   // 0..3071
  float v = (i < 2048) ? bq[i] : (i < 2560 ? bk[i-2048] : bv[i-2560]);
  outb[i] = v;
}

// v-part of qkv (bf16, rows 4096, cols 2560..3071 of ld 3072) -> Vt[b][kvh][d][t]
__global__ void k_vt(const short* __restrict__ qkv, short* __restrict__ Vt){
  __shared__ short tile[32][33];
  int tx = threadIdx.x, ty = threadIdx.y;
  int t0 = blockIdx.x*32, c0 = blockIdx.y*32;
  for (int j=0;j<32;j+=8)
    tile[ty+j][tx] = qkv[(size_t)(t0+ty+j)*3072 + 2560 + c0 + tx];
  __syncthreads();
  int b = t0 >> 11, t_in_b = t0 & 2047;
  for (int j=0;j<32;j+=8){
    int col = c0 + ty + j;               // 0..511
    int kvh = col >> 7, d = col & 127;
    Vt[((size_t)((b*4 + kvh)*128 + d))*2048 + t_in_b + tx] = tile[tx][ty+j];
  }
}

// ---------------- m97-style GEMM: C = A * Bt^T + bias ----------------
template<int OUT_BF16>
__global__ __launch_bounds__(256) void gemm_bt(const short* __restrict__ A,
    const short* __restrict__ Bt, const float* __restrict__ bias,
    void* __restrict__ Cv, int M, int N, int K){
  __shared__ short As[128*32];
  __shared__ short Bs[128*32];
  const int tid = threadIdx.x;
  const int w = tid >> 6, lane = tid & 63, l15 = lane & 15, quad = lane >> 4;
  const int wr = w >> 1, wc = w & 1;
  const int m0 = blockIdx.y*128, n0 = blockIdx.x*128;
  const int lrow = lane >> 2, lcol = (lane & 3)*8;
  const short* Ag = A  + (size_t)(m0 + w*32 + lrow)*K + lcol;
  const short* Bg = Bt + (size_t)(n0 + w*32 + lrow)*K + lcol;
  short* AsW0 = &As[(w*32)*32];
  short* AsW1 = &As[(w*32+16)*32];
  short* BsW0 = &Bs[(w*32)*32];
  short* BsW1 = &Bs[(w*32+16)*32];
  const size_t r16K = (size_t)16*K;
  f32x4 acc[4][4] = {};
  for (int kt = 0; kt < K; kt += 32){
    gld16(AsW0, Ag + kt);
    gld16(AsW1, Ag + kt + r16K);
    gld16(BsW0, Bg + kt);
    gld16(BsW1, Bg + kt + r16K);
    __syncthreads();
    bf16x8 af[4], bfr[4];
#pragma unroll
    for (int i=0;i<4;i++){
      af[i]  = *(const bf16x8*)&As[(wr*64 + i*16 + l15)*32 + quad*8];
      bfr[i] = *(const bf16x8*)&Bs[(wc*64 + i*16 + l15)*32 + quad*8];
    }
#pragma unroll
    for (int mi=0;mi<4;mi++)
#pragma unroll
      for (int nj=0;nj<4;nj++)
        acc[mi][nj] = MFMA16(af[mi], bfr[nj], acc[mi][nj]);
    __syncthreads();
  }
  float bv[4];
#pragma unroll
  for (int nj=0;nj<4;nj++) bv[nj] = bias[n0 + wc*64 + nj*16 + l15];
#pragma unroll
  for (int mi=0;mi<4;mi++){
    int row = m0 + wr*64 + mi*16 + quad*4;
#pragma unroll
    for (int nj=0;nj<4;nj++){
      int col = n0 + wc*64 + nj*16 + l15;
#pragma unroll
      for (int r=0;r<4;r++){
        float v = acc[mi][nj][r] + bv[nj];
        if (OUT_BF16) ((short*)Cv)[(size_t)(row+r)*N + col] = f2bf(v);
        else          ((float*)Cv)[(size_t)(row+r)*N + col] = v;
      }
    }
  }
}

// ---------------- balanced, async-pipelined causal GQA attention ----------
// 128 threads (2 waves x 32 q). Block = pair of q-tiles (qi, 31-qi) at BQ=64
// -> uniform 66 s-tile iters/block. Double-buffered LDS, K/V staged with
// global_load_lds into XOR-swizzled unpadded tiles, ONE barrier per iter.
// S^T = K*Q^T (16x16x32), P in registers, O^T += V^T*P^T (16x16x16).
__global__ __launch_bounds__(128) void k_attn(const short* __restrict__ qkv,
                                              const short* __restrict__ Vt,
                                              short* __restrict__ attn){
  constexpr float COEF = 0.12752365f;     // (1/sqrt(128)) * log2(e)
  __shared__ short SM[16384];             // 2 buffers x (K 4096 + V 4096 shorts)
  const int tid = threadIdx.x, w = tid >> 6, lane = tid & 63;
  const int l15 = lane & 15, quad = lane >> 4;
  const int p = blockIdx.x, h = blockIdx.y, b = blockIdx.z, kvh = h >> 2;

  // staging source pointers (per-lane, s0=0); slot = waveBase + laneIdx
  const short* kb[4];
  const short* vb[4];
#pragma unroll
  for (int j=0;j<4;j++){
    int rK = w*16 + j*4 + (lane >> 4);
    int cK = (lane & 15) ^ (rK & 15);
    kb[j] = qkv + (size_t)(b*2048 + rK)*3072 + 2048 + kvh*128 + cK*8;
    int dV = w*64 + j*16 + (lane >> 2);
    int cV = (lane & 3) ^ (dV & 3);
    vb[j] = Vt + ((size_t)((b*4 + kvh)*128 + dV))*2048 + cV*8;
  }
  short* KdstBase0 = &SM[0       + w*256*8];   // wave's slot base, buf 0
  short* VdstBase0 = &SM[4096    + w*256*8];

  int buf = 0;
  // prologue: stage tile 0 of strip 0 into buf 0
#pragma unroll
  for (int j=0;j<4;j++){
    gld16(KdstBase0 + j*512, kb[j]);
    gld16(VdstBase0 + j*512, vb[j]);
  }

  for (int sp = 0; sp < 2; sp++){
    const int qi = sp ? (31 - p) : p;
    const int qw = qi*64 + w*32;
    // Q fragments from global (B-operand layout: lane q=l15, k contiguous)
    bf16x8 qf[2][4];
    {
      const short* qbase = qkv + ((size_t)(b*2048 + qw + l15))*3072 + h*128 + quad*8;
#pragma unroll
      for (int qs=0;qs<2;qs++)
#pragma unroll
        for (int d4=0;d4<4;d4++)
          qf[qs][d4] = *(const bf16x8*)(qbase + (size_t)qs*16*3072 + d4*32);
    }
    f32x4 accO[2][8] = {};
    float lsum[2] = {0.f, 0.f};
    const int nst = 2*qi + 2;

    for (int st = 0; st < nst; st++){
      __syncthreads();                       // tile(st) in LDS[buf] complete
      const int cur = buf;
      const int nb = buf ^ 1;
      // async-stage next tile (or next strip's tile 0) into other buffer
      {
        int nxt = -1;
        if (st + 1 < nst) nxt = (st + 1) * 32;
        else if (sp == 0) nxt = 0;
        if (nxt >= 0){
          short* Kd = &SM[nb*8192 + w*256*8];
          short* Vd = &SM[nb*8192 + 4096 + w*256*8];
          const size_t ko = (size_t)nxt * 3072;
#pragma unroll
          for (int j=0;j<4;j++){
            gld16(Kd + j*512, kb[j] + ko);
            gld16(Vd + j*512, vb[j] + nxt);
          }
        }
      }
      const int s0 = st * 32;
      if (s0 <= qw + 31){                    // wave-uniform skip
        const short* Kb = &SM[cur*8192];
        const short* Vb = &SM[cur*8192 + 4096];
        bf16x8 kf[2][4];
#pragma unroll
        for (int ss=0;ss<2;ss++)
#pragma unroll
          for (int d4=0;d4<4;d4++){
            int slot = (ss*16 + l15)*16 + ((d4*4 + quad) ^ l15);
            kf[ss][d4] = *(const bf16x8*)&Kb[slot*8];
          }
        short4v pf[2][2];
#pragma unroll
        for (int qs=0;qs<2;qs++){
          f32x4 sa[2] = {};
#pragma unroll
          for (int d4=0;d4<4;d4++){
            sa[0] = MFMA16(kf[0][d4], qf[qs][d4], sa[0]);
            sa[1] = MFMA16(kf[1][d4], qf[qs][d4], sa[1]);
          }
          const int qmin = qw + qs*16;
          const bool mneed = (s0 + 31 > qmin);
          const int qgl = qmin + l15;
#pragma unroll
          for (int sub=0;sub<2;sub++){
            float pr[4];
#pragma unroll
            for (int r=0;r<4;r++){
              float e = __builtin_amdgcn_exp2f(sa[sub][r] * COEF);
              int sg = s0 + sub*16 + quad*4 + r;
              if (mneed && (sg > qgl)) e = 0.f;
              pr[r] = e;
            }
            lsum[qs] += (pr[0]+pr[1]) + (pr[2]+pr[3]);
            union { unsigned u[2]; short4v s; } pk;
            pk.u[0] = __builtin_amdgcn_perm(bits(pr[1]), bits(pr[0]), 0x07060302u);
            pk.u[1] = __builtin_amdgcn_perm(bits(pr[3]), bits(pr[2]), 0x07060302u);
            pf[qs][sub] = pk.s;
          }
        }
        // O^T += V^T * P^T
#pragma unroll
        for (int sub=0;sub<2;sub++)
#pragma unroll
          for (int dt=0;dt<8;dt++){
            int slot = (dt*16 + l15)*4 + ((sub*2 + (quad>>1)) ^ (l15 & 3));
            short4v vf = *(const short4v*)&Vb[slot*8 + (quad&1)*4];
            accO[0][dt] = MFMA16K(vf, pf[0][sub], accO[0][dt]);
            accO[1][dt] = MFMA16K(vf, pf[1][sub], accO[1][dt]);
          }
      }
      buf = nb;
    }
    // normalize + store this strip
#pragma unroll
    for (int qs=0;qs<2;qs++){
      float s = lsum[qs];
      s += __shfl_xor(s, 16);
      s += __shfl_xor(s, 32);
      float inv = 1.0f / s;
      short* obase = attn + ((size_t)(b*2048 + qw + qs*16 + l15))*2048
                   + h*128 + quad*4;
#pragma unroll
      for (int dt=0;dt<8;dt++){
        float o0 = accO[qs][dt][0]*inv, o1 = accO[qs][dt][1]*inv;
        float o2 = accO[qs][dt][2]*inv, o3 = accO[qs][dt][3]*inv;
        union { unsigned u[2]; short4v s; } ok;
        ok.u[0] = __builtin_amdgcn_perm(bits(o1), bits(o0), 0x07060302u);
        ok.u[1] = __builtin_amdgcn_perm(bits(o3), bits(o2), 0x07060302u);
        *(short4v*)(obase + dt*16) = ok.s;
      }
    }
  }
}

// ---------------- launcher ----------------
extern "C" void kernel_launch(void* const* d_in, const int* in_sizes, int n_in,
                              void* d_out, int out_size, void* d_ws, size_t ws_size,
                              hipStream_t stream){
  const float* x  = (const float*)d_in[0];
  const float* Wq = (const float*)d_in[1];
  const float* bq = (const float*)d_in[2];
  const float* Wk = (const float*)d_in[3];
  const float* bk = (const float*)d_in[4];
  const float* Wv = (const float*)d_in[5];
  const float* bv = (const float*)d_in[6];
  const float* Wo = (const float*)d_in[7];
  const float* bo = (const float*)d_in[8];
  float* out = (float*)d_out;
  char* ws = (char*)d_ws;

  short* xb    = (short*)(ws + 0);                        // 16 MB
  short* WtQKV = (short*)(ws + (size_t)16*1024*1024);     // 12 MB [3072][2048]
  short* WoT   = (short*)(ws + (size_t)28*1024*1024);     //  8 MB [2048][2048]
  float* biasQ = (float*)(ws + (size_t)36*1024*1024);     // 12 KB
  short* qkv   = (short*)(ws + (size_t)37*1024*1024);     // 24 MB [4096][3072]
  short* Vt    = (short*)(ws + (size_t)61*1024*1024);     //  4 MB [B][KVH][128][2048]
  short* attn  = (short*)(ws + 0);                        // overlay xb (disjoint lifetime)

  k_cvt8<<<4096, 256, 0, stream>>>(x, xb);
  k_wt<<<dim3(64,64), dim3(32,8), 0, stream>>>(Wq, WtQKV, 2048);
  k_wt<<<dim3(16,64), dim3(32,8), 0, stream>>>(Wk, WtQKV + (size_t)2048*2048, 512);
  k_wt<<<dim3(16,64), dim3(32,8), 0, stream>>>(Wv, WtQKV + (size_t)2560*2048, 512);
  k_wt<<<dim3(64,64), dim3(32,8), 0, stream>>>(Wo, WoT, 2048);
  k_bias<<<12, 256, 0, stream>>>(bq, bk, bv, biasQ);
  gemm_bt<1><<<dim3(24,32), 256, 0, stream>>>(xb, WtQKV, biasQ, qkv, 4096, 3072, 2048);
  k_vt<<<dim3(128,16), dim3(32,8), 0, stream>>>(qkv, Vt);
  k_attn<<<dim3(16,16,2), 128, 0, stream>>>(qkv, Vt, attn);
  gemm_bt<0><<<dim3(16,32), 256, 0, stream>>>(attn, WoT, bo, out, 4096, 2048, 2048);
}